// Round 2
// 759.615 us; speedup vs baseline: 1.0152x; 1.0152x over previous
//
#include <hip/hip_runtime.h>

// Vanilla tanh RNN. B=64, T=2048, I=64, H=128, fp32.
//   xw[b,t,h] = sum_i x[b,t,i]*W[h,i] + b_ih[h] + b_hh[h]
//   h_t = tanh(xw_t + h_{t-1} @ U^T);  outputs: ys [B,T,H], h_last [B,H]
//
// R6 theory: R5 scan = 665us = ~780 cyc/step. Per step the CU pulls
// 512 thr x 128 B = 64 KB of h-broadcast from LDS; at ~85 B/cyc/CU
// ds_read return BW that is ~770 cyc -> scan is LDS-return-BW bound
// (fits VALUBusy=13%, conflicts=0, and dur almost exactly). Broadcast
// does not collapse return BW (per-lane return path). Volume lever is
// rows-per-thread R (vol = 64KB/R): this version moves R=1 -> R=4.
//   scan: 256 thr (4 waves, 1/SIMD). thread(g=tid>>3, j=tid&7) owns
//         U rows 4g..4g+3 x k-slice [16j,16j+16) = 16 float4 (64 VGPR,
//         kept small on purpose: R1-R3 showed the allocator dropping
//         big per-thread weight arrays). Per step: 4x ds_read_b128
//         (16 KB/CU/step total), 16 fma4, 8-lane DPP butterfly
//         xor1(0xB1)+xor2(0x4E)+half_mirror(0x141, =xor7 within 8):
//         {1,2,7} generates Z2^3 -> full sums in all 8 lanes.
//         lane j<4 writes h'[4g+j], lane j>=4 writes out[4g+j-4].
//         h skew: h[k] at float off (k>>4)*20 + (k&15): slice bases
//         20j%32 hit 8 distinct bank-quads, 80B is float4-aligned.
//   gemm: same restructure (was ~105us, also LDS-broadcast-bound):
//         wave-half owns 64 W-rows, lane(g2=lane>>2, q2=lane&3) owns
//         rows 4g2..+3 x k[16q2,16q2+16); quad butterfly; row_own=lane
//         -> perfectly coalesced dword stores.
// (R7 = R6 resubmitted verbatim: R6 bench hit GPUAcquisitionTimeout,
//  no measurement was taken.)

#define RNN_B 64
#define RNN_T 2048
#define RNN_I 64
#define RNN_H 128
#define CH    32            // timesteps per staged chunk
#define NCH   (RNN_T / CH)  // 64 chunks

__device__ __forceinline__ float fast_tanh(float x) {
  // tanh(x) = 1 - 2/(e^{2x}+1);  e^{2x} = exp2(x * 2*log2(e))
  float e = __builtin_amdgcn_exp2f(x * 2.885390081777927f);
  return 1.0f - 2.0f * __builtin_amdgcn_rcpf(e + 1.0f);
}

template <int CTRL>
__device__ __forceinline__ float dpp_add(float s) {
  int o = __builtin_amdgcn_mov_dpp(__float_as_int(s), CTRL, 0xF, 0xF, true);
  return s + __int_as_float(o);
}

__device__ __forceinline__ void fma4(float4& a, const float4 u, const float4 h) {
  a.x = fmaf(u.x, h.x, a.x);
  a.y = fmaf(u.y, h.y, a.y);
  a.z = fmaf(u.z, h.z, a.z);
  a.w = fmaf(u.w, h.w, a.w);
}

__device__ __forceinline__ float hsum(const float4 a) {
  return (a.x + a.y) + (a.z + a.w);
}

// ---------------------------------------------------------------------------
// Kernel 1: xw = x @ W^T + (b_ih + b_hh).  M=B*T=131072, N=128, K=64.
// 2048 blocks x 256 threads, 64 x-rows/block.
// whalf=wave&1 owns W rows [64*whalf, 64*whalf+64); pair=wave>>1 processes
// x-rows [32*pair, 32*pair+32). lane -> (g2=lane>>2: rows 4g2..4g2+3,
// q2=lane&3: k-slice [16q2,16q2+16)): 16 float4 of W in regs.
// Quad butterfly -> all 4 lanes hold all 4 row sums; lane keeps row
// 4g2+q2, i.e. global row 64*whalf+lane -> coalesced dword store.
// LDS x-broadcast volume: 2MB/R = 512KB/block (was 2MB).
// ---------------------------------------------------------------------------
__global__ __launch_bounds__(256, 2) void rnn_xw_gemm(
    const float* __restrict__ x, const float* __restrict__ W,
    const float* __restrict__ b_ih, const float* __restrict__ b_hh,
    float* __restrict__ xw) {
  const int tid   = threadIdx.x;
  const int wave  = tid >> 6;
  const int lane  = tid & 63;
  const int whalf = wave & 1;
  const int pair  = wave >> 1;
  const int g2    = lane >> 2;
  const int q2    = lane & 3;

  // W tile: rows 64*whalf + 4g2 .. +3, cols [16q2, 16q2+16) -> 16 float4
  float4 w[4][4];
#pragma unroll
  for (int r = 0; r < 4; ++r) {
    const float4* Wr =
        (const float4*)(W + (64 * whalf + 4 * g2 + r) * RNN_I + 16 * q2);
#pragma unroll
    for (int m = 0; m < 4; ++m) w[r][m] = Wr[m];
  }
  const int row_own = 64 * whalf + lane;
  const float bias  = b_ih[row_own] + b_hh[row_own];

  // Stage 64 rows of x (64x64 fp32 = 16 KB) into LDS, coalesced.
  __shared__ __align__(16) float4 xs[64 * 16];
  const long rbase = (long)blockIdx.x * 64;
  const float4* xg = (const float4*)(x + rbase * RNN_I);
#pragma unroll
  for (int jj = 0; jj < 4; ++jj) xs[tid + 256 * jj] = xg[tid + 256 * jj];
  __syncthreads();

  for (int i = 0; i < 32; ++i) {
    const int r = 32 * pair + i;
    const float4* xr = xs + r * 16 + q2 * 4;
    float4 a0 = {0,0,0,0}, a1 = {0,0,0,0}, a2 = {0,0,0,0}, a3 = {0,0,0,0};
#pragma unroll
    for (int m = 0; m < 4; ++m) {
      const float4 xv = xr[m];
      fma4(a0, w[0][m], xv);
      fma4(a1, w[1][m], xv);
      fma4(a2, w[2][m], xv);
      fma4(a3, w[3][m], xv);
    }
    float s0 = hsum(a0), s1 = hsum(a1), s2 = hsum(a2), s3 = hsum(a3);
    s0 = dpp_add<0xB1>(s0); s0 = dpp_add<0x4E>(s0);
    s1 = dpp_add<0xB1>(s1); s1 = dpp_add<0x4E>(s1);
    s2 = dpp_add<0xB1>(s2); s2 = dpp_add<0x4E>(s2);
    s3 = dpp_add<0xB1>(s3); s3 = dpp_add<0x4E>(s3);
    const float own = (q2 & 2) ? ((q2 & 1) ? s3 : s2)
                               : ((q2 & 1) ? s1 : s0);
    xw[(rbase + r) * RNN_H + row_own] = own + bias;  // coalesced: row_own==64*whalf+lane
  }
}

// ---------------------------------------------------------------------------
// Kernel 2: sequential scan. 1 block/batch, 256 threads (4 waves, 1/SIMD).
// thread -> (g=tid>>3: U rows 4g..4g+3, j=tid&7: k-slice [16j,16j+16)):
// 16 float4 of U in regs (64 VGPRs). 16 KB/step/CU h-broadcast (was 64KB).
// 8-lane butterfly: xor1 + xor2 + half_mirror(0x141) -> full sums in all
// 8 lanes; lane j<4 writes next-h for row 4g+j (skewed slot), lane j>=4
// writes obuf for row 4g+(j-4). Ping-pong h buffers are compile-time
// (chunk = 32 steps, even), so no runtime cur arithmetic.
// ---------------------------------------------------------------------------
__global__ __launch_bounds__(256, 1) void rnn_scan(
    const float* xw,            // aliases `out` — no __restrict__
    float* out, float* __restrict__ hlast,
    const float* __restrict__ h0, const float* __restrict__ U) {
  const int b     = blockIdx.x;
  const int tid   = threadIdx.x;  // 0..255
  const int g     = tid >> 3;     // 0..31
  const int j     = tid & 7;      // k-slice
  const int r_own = 4 * g + (j & 3);

  __shared__ __align__(16) float hbuf0[8 * 20];     // skewed h state
  __shared__ __align__(16) float hbuf1[8 * 20];
  __shared__ __align__(16) float xbuf[CH * RNN_H];  // 16 KB
  __shared__ __align__(16) float obuf[CH * RNN_H];  // 16 KB

  // U tile: rows 4g..4g+3, cols [16j, 16j+16) -> 16 float4 (64 VGPRs)
  float4 u[4][4];
#pragma unroll
  for (int r = 0; r < 4; ++r) {
    const float4* Ur = (const float4*)(U + (4 * g + r) * RNN_H + 16 * j);
#pragma unroll
    for (int m = 0; m < 4; ++m) u[r][m] = Ur[m];
  }

  if (tid < RNN_H)
    hbuf0[(tid >> 4) * 20 + (tid & 15)] = h0[b * RNN_H + tid];

  const int hoff = (r_own >> 4) * 20 + (r_own & 15);  // skewed write slot
  const long base   = (long)b * RNN_T * RNN_H;
  const float4* xw4 = (const float4*)(xw + base);
  float4* out4      = (float4*)(out + base);
  float4* xb4       = (float4*)xbuf;
  const float4* ob4 = (const float4*)obuf;

  auto step = [&](const float* src, float* dst, int tc) {
    const float xv = xbuf[tc * RNN_H + r_own];   // no h dependency: issues early
    const float4* hp = (const float4*)(src + 20 * j);
    float4 a0 = {0,0,0,0}, a1 = {0,0,0,0}, a2 = {0,0,0,0}, a3 = {0,0,0,0};
#pragma unroll
    for (int m = 0; m < 4; ++m) {
      const float4 hv = hp[m];
      fma4(a0, u[0][m], hv);
      fma4(a1, u[1][m], hv);
      fma4(a2, u[2][m], hv);
      fma4(a3, u[3][m], hv);
    }
    float s0 = hsum(a0), s1 = hsum(a1), s2 = hsum(a2), s3 = hsum(a3);
    s0 = dpp_add<0xB1>(s0); s0 = dpp_add<0x4E>(s0); s0 = dpp_add<0x141>(s0);
    s1 = dpp_add<0xB1>(s1); s1 = dpp_add<0x4E>(s1); s1 = dpp_add<0x141>(s1);
    s2 = dpp_add<0xB1>(s2); s2 = dpp_add<0x4E>(s2); s2 = dpp_add<0x141>(s2);
    s3 = dpp_add<0xB1>(s3); s3 = dpp_add<0x4E>(s3); s3 = dpp_add<0x141>(s3);
    const float own = (j & 2) ? ((j & 1) ? s3 : s2)
                              : ((j & 1) ? s1 : s0);
    const float val = fast_tanh(own + xv);
    // lane j<4: next-h writer; lane j>=4: output writer (branchless addr sel)
    float* wp = (j < 4) ? (dst + hoff) : (obuf + tc * RNN_H + r_own);
    *wp = val;
    __syncthreads();
  };

  for (int c = 0; c < NCH; ++c) {
    // Phase A: stage xw chunk c (1024 float4, 4/thread); flush out c-1.
#pragma unroll
    for (int jj = 0; jj < 4; ++jj)
      xb4[tid + 256 * jj] = xw4[(long)c * 1024 + tid + 256 * jj];
    if (c > 0) {
#pragma unroll
      for (int jj = 0; jj < 4; ++jj)
        out4[(long)(c - 1) * 1024 + tid + 256 * jj] = ob4[tid + 256 * jj];
    }
    __syncthreads();

    // Phase B: 32 steps, LDS-only traffic, compile-time h ping-pong.
    for (int tc = 0; tc < CH; tc += 2) {
      step(hbuf0, hbuf1, tc);
      step(hbuf1, hbuf0, tc + 1);
    }
  }

  // Final chunk flush + h_last (last step's barrier makes data visible)
#pragma unroll
  for (int jj = 0; jj < 4; ++jj)
    out4[(long)(NCH - 1) * 1024 + tid + 256 * jj] = ob4[tid + 256 * jj];
  if (tid < RNN_H)
    hlast[b * RNN_H + tid] = hbuf0[(tid >> 4) * 20 + (tid & 15)];
}

extern "C" void kernel_launch(void* const* d_in, const int* in_sizes, int n_in,
                              void* d_out, int out_size, void* d_ws, size_t ws_size,
                              hipStream_t stream) {
  const float* x    = (const float*)d_in[0];
  const float* h0   = (const float*)d_in[1];
  const float* W    = (const float*)d_in[2];
  const float* U    = (const float*)d_in[3];
  const float* b_ih = (const float*)d_in[4];
  const float* b_hh = (const float*)d_in[5];

  float* out   = (float*)d_out;                           // [B,T,H]
  float* hlast = out + (long)RNN_B * RNN_T * RNN_H;       // [B,H]

  // Stage 1: xw into the output region (read-before-write in scan, per chunk)
  rnn_xw_gemm<<<(RNN_B * RNN_T) / 64, 256, 0, stream>>>(x, W, b_ih, b_hh, out);
  // Stage 2: sequential recurrence, one block per batch element
  rnn_scan<<<RNN_B, 256, 0, stream>>>(out, out, hlast, h0, U);
}